// Round 2
// baseline (859.066 us; speedup 1.0000x reference)
//
#include <hip/hip_runtime.h>

typedef __attribute__((ext_vector_type(8))) short short8;
typedef __attribute__((ext_vector_type(4))) float f32x4;
typedef __attribute__((ext_vector_type(4))) unsigned short u16x4;

#define T_SIZE (1u << 22)
#define HMASK 0x3FFFFFu
#define P2H 2654435761u
#define P3H 805459861u

__constant__ float c_RES[24] = {
    16.f, 24.f, 36.f, 54.f, 81.f, 121.f, 182.f, 273.f, 410.f, 615.f,
    922.f, 1383.f, 2075.f, 3113.f, 4670.f, 7006.f, 10509.f, 15764.f,
    23646.f, 35469.f, 53204.f, 79806.f, 119709.f, 179563.f};

static __device__ __forceinline__ ushort f2bf(float f) {
    union { float f; unsigned u; } v; v.f = f;
    unsigned r = v.u + 0x7FFFu + ((v.u >> 16) & 1u);
    return (ushort)(r >> 16);
}
static __device__ __forceinline__ float bf2f(ushort u) {
    union { unsigned u; float f; } v; v.u = ((unsigned)u) << 16; return v.f;
}

// Transpose + bf16-convert W1 (96x256) and W2 (256x256) into ws: Wt[n][k].
__global__ void prep_weights(const float* __restrict__ W1, const float* __restrict__ W2,
                             ushort* __restrict__ Wt1, ushort* __restrict__ Wt2) {
    int id = blockIdx.x * 256 + threadIdx.x;
    if (id < 96 * 256) {
        int n = id / 96, k = id - n * 96;
        Wt1[id] = f2bf(W1[k * 256 + n]);
    }
    int id2 = id - 96 * 256;
    if (id2 >= 0 && id2 < 256 * 256) {
        int n = id2 >> 8, k = id2 & 255;
        Wt2[id2] = f2bf(W2[k * 256 + n]);
    }
}

// ---------------- encode: one thread per (point, level) --------------------
// feat layout: [B][64] uint words (256B rows). Word w of row p stored at
// w ^ ((p&7)<<2)  (XOR on byte bits 4-6) so the MLP's ds_read_b128 at row
// stride 256B is bank-conflict-free while global_load_lds stays linear.
__global__ __launch_bounds__(256, 6) void encode_kernel(
    const float4* __restrict__ coords,
    const float* __restrict__ stab,
    const float* __restrict__ ttab,
    unsigned* __restrict__ feat) {
    const unsigned idx = blockIdx.x * 256u + threadIdx.x;  // < B*24 exactly
    const unsigned p = idx / 24u;
    const unsigned l = idx - p * 24u;
    const float4 c = coords[p];
    const float R = c_RES[l];

    // spatial
    float sx = c.x * R, sy = c.y * R, sz = c.z * R;
    float bx = floorf(sx), by = floorf(sy), bz = floorf(sz);
    float fx = sx - bx, fy = sy - by, fz = sz - bz;
    unsigned ux = (unsigned)(int)bx, uy = (unsigned)(int)by, uz = (unsigned)(int)bz;
    unsigned hx0 = ux, hx1 = ux + 1u;
    unsigned hy0 = uy * P2H, hy1 = hy0 + P2H;
    unsigned hz0 = uz * P3H, hz1 = hz0 + P3H;
    const unsigned lb = l << 22;
    const float2* st = (const float2*)stab;
    float2 e[8];
    e[0] = st[lb + ((hx0 ^ hy0 ^ hz0) & HMASK)];
    e[1] = st[lb + ((hx0 ^ hy0 ^ hz1) & HMASK)];
    e[2] = st[lb + ((hx0 ^ hy1 ^ hz0) & HMASK)];
    e[3] = st[lb + ((hx0 ^ hy1 ^ hz1) & HMASK)];
    e[4] = st[lb + ((hx1 ^ hy0 ^ hz0) & HMASK)];
    e[5] = st[lb + ((hx1 ^ hy0 ^ hz1) & HMASK)];
    e[6] = st[lb + ((hx1 ^ hy1 ^ hz0) & HMASK)];
    e[7] = st[lb + ((hx1 ^ hy1 ^ hz1) & HMASK)];
    float wx0 = 1.f - fx, wy0 = 1.f - fy, wz0 = 1.f - fz;
    float w[8] = {wx0 * wy0 * wz0, wx0 * wy0 * fz, wx0 * fy * wz0, wx0 * fy * fz,
                  fx * wy0 * wz0,  fx * wy0 * fz,  fx * fy * wz0,  fx * fy * fz};
    float f0 = 0.f, f1 = 0.f;
    #pragma unroll
    for (int q = 0; q < 8; ++q) { f0 = fmaf(w[q], e[q].x, f0); f1 = fmaf(w[q], e[q].y, f1); }

    // temporal
    float stt = c.w * R;
    float bt = floorf(stt);
    float ft = stt - bt;
    unsigned ut = (unsigned)(int)bt;
    const float2* tt = (const float2*)ttab;
    float2 t0 = tt[lb + ((ut * P2H) & HMASK)];
    float2 t1 = tt[lb + (((ut + 1u) * P2H) & HMASK)];
    float g0 = (1.f - ft) * t0.x + ft * t1.x;
    float g1 = (1.f - ft) * t0.y + ft * t1.y;

    const unsigned sw = (p & 7u) << 2;
    const unsigned row = p << 6;
    feat[row + (l ^ sw)]          = (unsigned)f2bf(f0) | ((unsigned)f2bf(f1) << 16);
    feat[row + ((24u + l) ^ sw)]  = (unsigned)f2bf(g0) | ((unsigned)f2bf(g1) << 16);
}

// ---------------- MLP: 64 points/block, swapped-operand MFMA ---------------
// All layers computed as C^T: A = W^T[n][k] (global, contiguous), B = act[m][k]
// (LDS rows, contiguous), D[n][m] -> thread holds 4 consecutive n at fixed m
// -> packed 8B ds_write_b64 epilogue into act[m][n] row-major for next layer.
__global__ __launch_bounds__(256) void mlp_kernel(
    const unsigned* __restrict__ feat,
    const ushort* __restrict__ Wt1,
    const float* __restrict__ b1,
    const ushort* __restrict__ Wt2,
    const float* __restrict__ b2,
    const float* __restrict__ W3,
    const float* __restrict__ b3,
    float* __restrict__ out) {
    __shared__ __align__(16) ushort feat_lds[64 * 128];  // 16KB, swizzled rows
    __shared__ __align__(16) ushort h_lds[64 * 264];     // 33792B
    __shared__ float w3_lds[772];

    const int tid = threadIdx.x;
    const int lane = tid & 63, wv = tid >> 6;
    const int lr = lane & 15, chunk = lane >> 4;
    const int nb = wv * 64;

    for (int i = tid; i < 768; i += 256) w3_lds[i] = W3[i];
    if (tid < 3) w3_lds[768 + tid] = b3[tid];

    // stage feat tile (16KB): each wave copies 4KB in 4 x 1KB chunks
    {
        const char* g = (const char*)(feat + (size_t)blockIdx.x * 4096) + wv * 4096 + lane * 16;
        #pragma unroll
        for (int it = 0; it < 4; ++it)
            __builtin_amdgcn_global_load_lds(
                (const __attribute__((address_space(1))) unsigned*)(g + it * 1024),
                (__attribute__((address_space(3))) unsigned*)&feat_lds[wv * 2048 + it * 512],
                16, 0, 0);
    }
    __syncthreads();

    // ----- layer 1: K=96, D1T[n][m], wave owns n in [nb, nb+64)
    f32x4 acc[4][4] = {};
    #pragma unroll
    for (int ks = 0; ks < 3; ++ks) {
        short8 a[4], b[4];
        #pragma unroll
        for (int ni = 0; ni < 4; ++ni)
            a[ni] = *(const short8*)&Wt1[(size_t)(nb + ni * 16 + lr) * 96 + ks * 32 + chunk * 8];
        #pragma unroll
        for (int mi = 0; mi < 4; ++mi) {
            int m = mi * 16 + lr;
            int w = (ks * 16 + chunk * 4) ^ ((m & 7) << 2);
            b[mi] = *(const short8*)&feat_lds[m * 128 + 2 * w];
        }
        #pragma unroll
        for (int ni = 0; ni < 4; ++ni)
            #pragma unroll
            for (int mi = 0; mi < 4; ++mi)
                acc[ni][mi] = __builtin_amdgcn_mfma_f32_16x16x32_bf16(a[ni], b[mi], acc[ni][mi], 0, 0, 0);
    }
    #pragma unroll
    for (int ni = 0; ni < 4; ++ni) {
        float4 bn = *(const float4*)&b1[nb + ni * 16 + chunk * 4];
        #pragma unroll
        for (int mi = 0; mi < 4; ++mi) {
            u16x4 v;
            v.x = f2bf(fmaxf(acc[ni][mi][0] + bn.x, 0.f));
            v.y = f2bf(fmaxf(acc[ni][mi][1] + bn.y, 0.f));
            v.z = f2bf(fmaxf(acc[ni][mi][2] + bn.z, 0.f));
            v.w = f2bf(fmaxf(acc[ni][mi][3] + bn.w, 0.f));
            *(u16x4*)&h_lds[(mi * 16 + lr) * 264 + nb + ni * 16 + chunk * 4] = v;
        }
    }
    __syncthreads();

    // ----- layer 2: K=256
    f32x4 acc2[4][4] = {};
    #pragma unroll
    for (int ks = 0; ks < 8; ++ks) {
        short8 a[4], b[4];
        #pragma unroll
        for (int ni = 0; ni < 4; ++ni)
            a[ni] = *(const short8*)&Wt2[(size_t)(nb + ni * 16 + lr) * 256 + ks * 32 + chunk * 8];
        #pragma unroll
        for (int mi = 0; mi < 4; ++mi)
            b[mi] = *(const short8*)&h_lds[(mi * 16 + lr) * 264 + ks * 32 + chunk * 8];
        #pragma unroll
        for (int ni = 0; ni < 4; ++ni)
            #pragma unroll
            for (int mi = 0; mi < 4; ++mi)
                acc2[ni][mi] = __builtin_amdgcn_mfma_f32_16x16x32_bf16(a[ni], b[mi], acc2[ni][mi], 0, 0, 0);
    }
    __syncthreads();  // all h1 reads done before overwrite
    #pragma unroll
    for (int ni = 0; ni < 4; ++ni) {
        float4 bn = *(const float4*)&b2[nb + ni * 16 + chunk * 4];
        #pragma unroll
        for (int mi = 0; mi < 4; ++mi) {
            u16x4 v;
            v.x = f2bf(fmaxf(acc2[ni][mi][0] + bn.x, 0.f));
            v.y = f2bf(fmaxf(acc2[ni][mi][1] + bn.y, 0.f));
            v.z = f2bf(fmaxf(acc2[ni][mi][2] + bn.z, 0.f));
            v.w = f2bf(fmaxf(acc2[ni][mi][3] + bn.w, 0.f));
            *(u16x4*)&h_lds[(mi * 16 + lr) * 264 + nb + ni * 16 + chunk * 4] = v;
        }
    }
    __syncthreads();

    // ----- layer 3 + sigmoid
    if (tid < 192) {
        const int pp = tid / 3;
        const int cc = tid - 3 * pp;
        float s = w3_lds[768 + cc];
        #pragma unroll 8
        for (int k = 0; k < 256; ++k)
            s = fmaf(bf2f(h_lds[pp * 264 + k]), w3_lds[k * 3 + cc], s);
        out[(size_t)(blockIdx.x * 64 + pp) * 3 + cc] = 1.f / (1.f + expf(-s));
    }
}

// ---------------- fallback (R1 fused kernel) if ws too small ---------------
#define FLD 104
#define HLD 264
__global__ __launch_bounds__(256) void fused_ngp_fb(
    const float4* __restrict__ coords, const float* __restrict__ stab,
    const float* __restrict__ ttab, const ushort* __restrict__ Wt1,
    const float* __restrict__ b1, const ushort* __restrict__ Wt2,
    const float* __restrict__ b2, const float* __restrict__ W3,
    const float* __restrict__ b3, float* __restrict__ out) {
    __shared__ ushort feat_lds[64 * FLD];
    __shared__ ushort h_lds[64 * HLD];
    __shared__ float w3_lds[772];
    const int tid = threadIdx.x;
    for (int i = tid; i < 768; i += 256) w3_lds[i] = W3[i];
    if (tid < 3) w3_lds[768 + tid] = b3[tid];
    const int p = tid & 63;
    const int g = tid >> 6;
    const float4 c = coords[blockIdx.x * 64 + p];
    #pragma unroll
    for (int dl = 0; dl < 6; ++dl) {
        const int l = g * 6 + dl;
        const float R = c_RES[l];
        float sx = c.x * R, sy = c.y * R, sz = c.z * R;
        float bx = floorf(sx), by = floorf(sy), bz = floorf(sz);
        float fx = sx - bx, fy = sy - by, fz = sz - bz;
        unsigned ux = (unsigned)(int)bx, uy = (unsigned)(int)by, uz = (unsigned)(int)bz;
        unsigned hx0 = ux, hx1 = ux + 1u;
        unsigned hy0 = uy * P2H, hy1 = hy0 + P2H;
        unsigned hz0 = uz * P3H, hz1 = hz0 + P3H;
        const float2* tl = (const float2*)stab + (size_t)l * T_SIZE;
        unsigned h[8];
        h[0] = (hx0 ^ hy0 ^ hz0) & HMASK; h[1] = (hx0 ^ hy0 ^ hz1) & HMASK;
        h[2] = (hx0 ^ hy1 ^ hz0) & HMASK; h[3] = (hx0 ^ hy1 ^ hz1) & HMASK;
        h[4] = (hx1 ^ hy0 ^ hz0) & HMASK; h[5] = (hx1 ^ hy0 ^ hz1) & HMASK;
        h[6] = (hx1 ^ hy1 ^ hz0) & HMASK; h[7] = (hx1 ^ hy1 ^ hz1) & HMASK;
        float2 e[8];
        #pragma unroll
        for (int q = 0; q < 8; ++q) e[q] = tl[h[q]];
        float wx0 = 1.f - fx, wy0 = 1.f - fy, wz0 = 1.f - fz;
        float w[8] = {wx0 * wy0 * wz0, wx0 * wy0 * fz, wx0 * fy * wz0, wx0 * fy * fz,
                      fx * wy0 * wz0,  fx * wy0 * fz,  fx * fy * wz0,  fx * fy * fz};
        float f0 = 0.f, f1 = 0.f;
        #pragma unroll
        for (int q = 0; q < 8; ++q) { f0 = fmaf(w[q], e[q].x, f0); f1 = fmaf(w[q], e[q].y, f1); }
        feat_lds[p * FLD + 2 * l] = f2bf(f0);
        feat_lds[p * FLD + 2 * l + 1] = f2bf(f1);
        float stv = c.w * R;
        float btf = floorf(stv);
        float ftv = stv - btf;
        unsigned utv = (unsigned)(int)btf;
        const float2* ttl = (const float2*)ttab + (size_t)l * T_SIZE;
        float2 e0 = ttl[(utv * P2H) & HMASK], e1 = ttl[((utv + 1u) * P2H) & HMASK];
        feat_lds[p * FLD + 48 + 2 * l] = f2bf((1.f - ftv) * e0.x + ftv * e1.x);
        feat_lds[p * FLD + 48 + 2 * l + 1] = f2bf((1.f - ftv) * e0.y + ftv * e1.y);
    }
    __syncthreads();
    const int lane = tid & 63;
    const int wv = tid >> 6;
    const int lr = lane & 15;
    const int lk = (lane >> 4) * 8;
    const int nb = wv * 64;
    const int rbase = (lane >> 4) * 4;
    f32x4 acc[4][4] = {};
    #pragma unroll
    for (int ks = 0; ks < 3; ++ks) {
        short8 a[4], b[4];
        #pragma unroll
        for (int mi = 0; mi < 4; ++mi)
            a[mi] = *(const short8*)&feat_lds[(mi * 16 + lr) * FLD + ks * 32 + lk];
        #pragma unroll
        for (int ni = 0; ni < 4; ++ni)
            b[ni] = *(const short8*)&Wt1[(size_t)(nb + ni * 16 + lr) * 96 + ks * 32 + lk];
        #pragma unroll
        for (int mi = 0; mi < 4; ++mi)
            #pragma unroll
            for (int ni = 0; ni < 4; ++ni)
                acc[mi][ni] = __builtin_amdgcn_mfma_f32_16x16x32_bf16(a[mi], b[ni], acc[mi][ni], 0, 0, 0);
    }
    {
        float bn[4];
        #pragma unroll
        for (int ni = 0; ni < 4; ++ni) bn[ni] = b1[nb + ni * 16 + lr];
        #pragma unroll
        for (int mi = 0; mi < 4; ++mi)
            #pragma unroll
            for (int ni = 0; ni < 4; ++ni)
                #pragma unroll
                for (int r = 0; r < 4; ++r)
                    h_lds[(mi * 16 + rbase + r) * HLD + nb + ni * 16 + lr] =
                        f2bf(fmaxf(acc[mi][ni][r] + bn[ni], 0.f));
    }
    __syncthreads();
    f32x4 acc2[4][4] = {};
    #pragma unroll
    for (int ks = 0; ks < 8; ++ks) {
        short8 a[4], b[4];
        #pragma unroll
        for (int mi = 0; mi < 4; ++mi)
            a[mi] = *(const short8*)&h_lds[(mi * 16 + lr) * HLD + ks * 32 + lk];
        #pragma unroll
        for (int ni = 0; ni < 4; ++ni)
            b[ni] = *(const short8*)&Wt2[(size_t)(nb + ni * 16 + lr) * 256 + ks * 32 + lk];
        #pragma unroll
        for (int mi = 0; mi < 4; ++mi)
            #pragma unroll
            for (int ni = 0; ni < 4; ++ni)
                acc2[mi][ni] = __builtin_amdgcn_mfma_f32_16x16x32_bf16(a[mi], b[ni], acc2[mi][ni], 0, 0, 0);
    }
    __syncthreads();
    {
        float bn2[4];
        #pragma unroll
        for (int ni = 0; ni < 4; ++ni) bn2[ni] = b2[nb + ni * 16 + lr];
        #pragma unroll
        for (int mi = 0; mi < 4; ++mi)
            #pragma unroll
            for (int ni = 0; ni < 4; ++ni)
                #pragma unroll
                for (int r = 0; r < 4; ++r)
                    h_lds[(mi * 16 + rbase + r) * HLD + nb + ni * 16 + lr] =
                        f2bf(fmaxf(acc2[mi][ni][r] + bn2[ni], 0.f));
    }
    __syncthreads();
    if (tid < 192) {
        const int pp = tid / 3;
        const int cc = tid - 3 * pp;
        float s = w3_lds[768 + cc];
        #pragma unroll 8
        for (int k = 0; k < 256; ++k)
            s = fmaf(bf2f(h_lds[pp * HLD + k]), w3_lds[k * 3 + cc], s);
        out[(size_t)(blockIdx.x * 64 + pp) * 3 + cc] = 1.f / (1.f + expf(-s));
    }
}

extern "C" void kernel_launch(void* const* d_in, const int* in_sizes, int n_in,
                              void* d_out, int out_size, void* d_ws, size_t ws_size,
                              hipStream_t stream) {
    const float* coords = (const float*)d_in[0];
    const float* stab   = (const float*)d_in[1];
    const float* ttab   = (const float*)d_in[2];
    const float* W1     = (const float*)d_in[3];
    const float* b1     = (const float*)d_in[4];
    const float* W2     = (const float*)d_in[5];
    const float* b2     = (const float*)d_in[6];
    const float* W3     = (const float*)d_in[7];
    const float* b3     = (const float*)d_in[8];

    const int B = in_sizes[0] / 4;  // 262144
    const size_t FEAT_BYTES = (size_t)B * 256;        // bf16 [B][128]
    const size_t W_BYTES = (96 * 256 + 256 * 256) * 2;

    if (ws_size >= FEAT_BYTES + W_BYTES) {
        unsigned* feat = (unsigned*)d_ws;                       // [B][64] words
        ushort* Wt1 = (ushort*)((char*)d_ws + FEAT_BYTES);
        ushort* Wt2 = Wt1 + 96 * 256;
        prep_weights<<<352, 256, 0, stream>>>(W1, W2, Wt1, Wt2);
        encode_kernel<<<(B * 24) / 256, 256, 0, stream>>>(
            (const float4*)coords, stab, ttab, feat);
        mlp_kernel<<<B / 64, 256, 0, stream>>>(feat, Wt1, b1, Wt2, b2, W3, b3,
                                               (float*)d_out);
    } else {
        ushort* Wt1 = (ushort*)d_ws;
        ushort* Wt2 = Wt1 + 96 * 256;
        prep_weights<<<352, 256, 0, stream>>>(W1, W2, Wt1, Wt2);
        fused_ngp_fb<<<B / 64, 256, 0, stream>>>((const float4*)coords, stab, ttab,
                                                 Wt1, b1, Wt2, b2, W3, b3,
                                                 (float*)d_out);
    }
}